// Round 1
// baseline (176.021 us; speedup 1.0000x reference)
//
#include <hip/hip_runtime.h>

#define MAXN 128

// ===== continued-fraction kernel: single-wave blocks, 2 lanes/row, fp32 ======
// 1/G_j = d_j - e_j - c_j,  e_j = bc_{j-1}/F_{j-1},  c_j = bc_j/W_{j+1}
// F_j = d_j - e_j (ratio theta_{j+1}/theta_j), W_j = d_j - c_j (phi_j/phi_{j+1})
// Im(F),Im(W) <= -1 always => O(1) magnitudes, fp32 + v_rcp stable.
// Lanes 0-31 (A) run forward on rows 0-31; lanes 32-63 (B) run backward on the
// same rows. Handoff F_39 <-> W_40 via shfl_xor(32).
//
// v2 (this round): each lane's 40-column half of `a` is transposed into
// registers once (20x ds_read_b64); the per-step LDS reads are gone and the
// sA LDS region is reused as the output-staging buffer. LDS 15.6K -> 11.1K,
// residency 10 -> 12-14 blocks/CU, to smooth the bursty HBM request stream
// (kernel is memory-bound: 125.8 MB mandatory traffic, floor ~19 us).
template<int N>
__global__ __launch_bounds__(64, 3) void greens_cf1w(
    const float* __restrict__ he,    // (B, N)
    const float* __restrict__ h0d,   // (N)
    const float* __restrict__ h0sub, // (N-1)
    const float* __restrict__ h0sup, // (N-1)
    float2* __restrict__ out)        // (B, N)
{
    constexpr int ROWS = 32;
    constexpr int MID  = N / 2;      // 40
    constexpr int LDA  = 84;         // row stride in floats: 336B, 16B-aligned
    static_assert(N == 80, "tuned for N=80");

    __shared__ float sA[ROWS][LDA];  // a = h0d + he; later REUSED as sO
    __shared__ float sBC[N];         // bc_j, j=0..N-2

    const int t = threadIdx.x;
    if (t < N - 1)      sBC[t]      = h0sub[t] * h0sup[t];
    if (t + 64 < N - 1) sBC[t + 64] = h0sub[t + 64] * h0sup[t + 64];

    const int row0 = blockIdx.x * ROWS;
    const float* __restrict__ tile  = he  + (size_t)row0 * N;
    float2*      __restrict__ otile = out + (size_t)row0 * N;

    // ---- stage a-tile, coalesced float4 (64 lanes x 16B = 1KB/instr) ----
    #pragma unroll
    for (int i = 0; i < (ROWS * N / 4) / 64; ++i) {   // 10 iters
        int idx = i * 64 + t;
        int rr  = idx / (N / 4);
        int q   = idx - rr * (N / 4);
        int col = q * 4;
        float4 v  = *(const float4*)(tile + (size_t)rr * N + col);
        float4 dv = *(const float4*)(h0d + col);
        *(float4*)&sA[rr][col] =
            make_float4(v.x + dv.x, v.y + dv.y, v.z + dv.z, v.w + dv.w);
    }
    __syncthreads();   // single-wave block: cheap

    const int  r   = t & 31;
    const bool isA = (t < 32);

    // ---- transpose-to-regs: lane owns its half-row in consumption order ----
    // A lane: aR[k] = a[k]        (cols 0..39)
    // B lane: aR[k] = a[N-1-k]    (cols 79..40)  -> same static index both dirs
    float aR[MID];
    {
        const float2* rowp = (const float2*)&sA[r][0];   // 8B-aligned (336B rows)
        #pragma unroll
        for (int k = 0; k < MID / 2; ++k) {              // 20x ds_read_b64
            float2 p = rowp[isA ? k : (MID / 2 - 1 - k + MID / 2)]; // k or 39-k
            aR[2 * k]     = isA ? p.x : p.y;
            aR[2 * k + 1] = isA ? p.y : p.x;
        }
    }
    // all sA reads drained before sA's memory is reused as sO below
    asm volatile("s_waitcnt lgkmcnt(0)" ::: "memory");

    float str_[MID - 1], sti_[MID - 1];   // 39 stored CF terms (e_j / c_j)
    float2 X = make_float2(aR[0], -1.0f); // F_0 = d_0 / W_{N-1} = d_{N-1}

    // ---- phase 1: 39 steps, store e_{s+1} (A) / c_{78-s} (B) at [s] ----
    #pragma unroll
    for (int s = 0; s < MID - 1; ++s) {
        int bci = isA ? s : (N - 2 - s);                // bc-index (broadcast)
        float inv  = __builtin_amdgcn_rcpf(X.x * X.x + X.y * X.y);
        float binv = sBC[bci] * inv;
        float ex =  binv * X.x;
        float ey = -binv * X.y;
        str_[s] = ex; sti_[s] = ey;
        X.x = aR[s + 1] - ex;                           // F_{s+1} / W_{78-s}
        X.y = -1.0f - ey;
    }

    // ---- handoff: A gets W_40, B gets F_39 (in-wave, no barrier) ----
    X.x = __shfl_xor(X.x, 32);
    X.y = __shfl_xor(X.y, 32);

    // ---- phase 2: finish opposite recursion, emit G, flush every 8 cols ----
    // sO overlays sA's first 4352 bytes (rows 0..12) — sA is dead now.
    float2 (*sO)[17] = reinterpret_cast<float2(*)[17]>(&sA[0][0]);
    #pragma unroll
    for (int b8 = 0; b8 < 5; ++b8) {
        #pragma unroll
        for (int u = 0; u < 8; ++u) {
            const int u2  = b8 * 8 + u;
            const int j   = isA ? (MID - 1 - u2) : (MID + u2);   // 39..0 / 40..79
            const int bci = isA ? (MID - 1 - u2) : (MID - 1 + u2);
            const int ak  = MID - 1 - u2;               // same static aR index
            float inv  = __builtin_amdgcn_rcpf(X.x * X.x + X.y * X.y);
            float binv = sBC[bci] * inv;
            float tx =  binv * X.x;                     // c_j (A) / e_j (B)
            float ty = -binv * X.y;
            float Xx = aR[ak] - tx;                     // W_j (A) / F_j (B)
            float Xy = -1.0f - ty;
            float ox = (u2 < MID - 1) ? str_[MID - 2 - u2] : 0.0f;
            float oy = (u2 < MID - 1) ? sti_[MID - 2 - u2] : 0.0f;
            float zx = Xx - ox;                         // 1/G_j
            float zy = Xy - oy;
            float gi = __builtin_amdgcn_rcpf(zx * zx + zy * zy);
            const int slot = isA ? (j & 7) : (8 + (j & 7));
            sO[r][slot] = make_float2(zx * gi, -zy * gi);
            X.x = Xx; X.y = Xy;
        }
        // wave-synchronous flush: 2 full 64B lines per 8-lane group, no barrier
        #pragma unroll
        for (int i = 0; i < 4; ++i) {
            int idx = i * 64 + t;
            int rr  = idx >> 3;
            int u   = idx & 7;
            int col = (u < 4) ? (MID - 8 - 8 * b8 + 2 * u)    // A chunk
                              : (MID - 8 + 8 * b8 + 2 * u);   // B chunk
            float2 g0 = sO[rr][2 * u];
            float2 g1 = sO[rr][2 * u + 1];
            *(float4*)(otile + (size_t)rr * N + col) =
                make_float4(g0.x, g0.y, g1.x, g1.y);
        }
    }
}

// ================= generic fallback (round-1 kernel, any N) ==================
__global__ __launch_bounds__(256) void greens_generic(
    const float* __restrict__ he,
    const float* __restrict__ h0d,
    const float* __restrict__ h0sub,
    const float* __restrict__ h0sup,
    float2* __restrict__ out,
    int Bn, int N)
{
    __shared__ float sa[MAXN];
    __shared__ float sbc[MAXN];
    const int t = threadIdx.x;
    if (t < N)     sa[t]  = h0d[t];
    if (t < N - 1) sbc[t] = h0sub[t] * h0sup[t];
    __syncthreads();

    const int b = blockIdx.x * blockDim.x + t;
    if (b >= Bn) return;

    const float* __restrict__ row  = he  + (size_t)b * N;
    float2*      __restrict__ orow = out + (size_t)b * N;

    double tpr = 1.0, tpi = 0.0;
    double tcr = (double)sa[0] + (double)row[0];
    double tci = -1.0;
    orow[0] = make_float2(1.0f, 0.0f);
    for (int k = 1; k < N; ++k) {
        orow[k] = make_float2((float)tcr, (float)tci);
        double ak = (double)sa[k] + (double)row[k];
        double bk = (double)sbc[k - 1];
        double nr = fma(ak, tcr,  tci) - bk * tpr;
        double ni = fma(ak, tci, -tcr) - bk * tpi;
        tpr = tcr; tpi = tci; tcr = nr; tci = ni;
    }
    const double dr = tcr, di = tci;
    const double inv = 1.0 / (dr * dr + di * di);
    const double cr  =  dr * inv;
    const double ci_ = -di * inv;

    double f1r = 1.0, f1i = 0.0;
    double f2r = 0.0, f2i = 0.0;
    for (int j = N - 1; j >= 0; --j) {
        float2 thv = orow[j];
        double tr = (double)thv.x, ti = (double)thv.y;
        double nr = tr * f1r - ti * f1i;
        double ni = tr * f1i + ti * f1r;
        orow[j] = make_float2((float)(nr * cr - ni * ci_),
                              (float)(nr * ci_ + ni * cr));
        double aj = (double)sa[j] + (double)row[j];
        double bj = (j < N - 1) ? (double)sbc[j] : 0.0;
        double pr = fma(aj, f1r,  f1i) - bj * f2r;
        double pi = fma(aj, f1i, -f1r) - bj * f2i;
        f2r = f1r; f2i = f1i; f1r = pr; f1i = pi;
    }
}

extern "C" void kernel_launch(void* const* d_in, const int* in_sizes, int n_in,
                              void* d_out, int out_size, void* d_ws, size_t ws_size,
                              hipStream_t stream) {
    const float* he    = (const float*)d_in[0];
    const float* h0d   = (const float*)d_in[1];
    const float* h0sub = (const float*)d_in[2];
    const float* h0sup = (const float*)d_in[3];
    const int N  = in_sizes[1];           // 80
    const int Bn = in_sizes[0] / N;       // 131072
    float2* out = (float2*)d_out;

    if (N == 80 && (Bn % 32) == 0) {
        const int grid = Bn / 32;
        hipLaunchKernelGGL((greens_cf1w<80>), dim3(grid), dim3(64), 0, stream,
                           he, h0d, h0sub, h0sup, out);
    } else {
        const int block = 256;
        const int grid  = (Bn + block - 1) / block;
        hipLaunchKernelGGL(greens_generic, dim3(grid), dim3(block), 0, stream,
                           he, h0d, h0sub, h0sup, out, Bn, N);
    }
}

// Round 3
// 131.737 us; speedup vs baseline: 1.3362x; 1.3362x over previous
//
#include <hip/hip_runtime.h>

#define MAXN 128

// native 16B vector type for nontemporal builtins (HIP float4 is a class)
typedef float floatx4 __attribute__((ext_vector_type(4)));

// ===== continued-fraction kernel: single-wave blocks, 2 lanes/row, fp32 ======
// 1/G_j = d_j - e_j - c_j,  e_j = bc_{j-1}/F_{j-1},  c_j = bc_j/W_{j+1}
// F_j = d_j - e_j (ratio theta_{j+1}/theta_j), W_j = d_j - c_j (phi_j/phi_{j+1})
// Im(F),Im(W) <= -1 always => O(1) magnitudes, fp32 + v_rcp stable.
// Lanes 0-31 (A) run forward on rows 0-31; lanes 32-63 (B) run backward on the
// same rows. Handoff F_39 <-> W_40 via shfl_xor(32). Branchless direction via
// lane-selected indices. No __syncthreads in the main loop (wave-synchronous).
//
// v4 = v3 with the nontemporal builtin type fixed (native ext_vector_type).
// Structure is the proven round-0 form:
//   - per-step sA LDS reads (bank-free: stride 81, odd => permutation)
//   - str_/sti_ (78 floats) in VGPRs, ~120 total, fits 4 waves/EU
//   - LDS 15.4KB -> 10 blocks/CU (LDS-bound; VGPR allows 16 -- LDS binds)
// Deltas vs round-0: nontemporal he loads / out stores (touch-once streams,
// skip L2 allocation), and clamped str_ index (no speculative str_[-1]).
template<int N>
__global__ __launch_bounds__(64, 4) void greens_cf1w(
    const float* __restrict__ he,    // (B, N)
    const float* __restrict__ h0d,   // (N)
    const float* __restrict__ h0sub, // (N-1)
    const float* __restrict__ h0sup, // (N-1)
    float2* __restrict__ out)        // (B, N)
{
    constexpr int ROWS = 32;
    constexpr int MID  = N / 2;      // 40
    static_assert(N == 80, "tuned for N=80");

    __shared__ float  sA[ROWS][N + 1];   // a = h0d + he; pad 81 -> conflict-free
    __shared__ float2 sO[ROWS][17];      // out staging: slots 0-7 A, 8-15 B
    __shared__ float  sBC[N];            // bc_j, j=0..N-2

    const int t = threadIdx.x;
    if (t < N - 1)      sBC[t]      = h0sub[t] * h0sup[t];
    if (t + 64 < N - 1) sBC[t + 64] = h0sub[t + 64] * h0sup[t + 64];

    const int row0 = blockIdx.x * ROWS;
    const float* __restrict__ tile  = he  + (size_t)row0 * N;
    float2*      __restrict__ otile = out + (size_t)row0 * N;

    // ---- stage a-tile, coalesced float4 (64 lanes x 16B = 1KB/instr) ----
    #pragma unroll
    for (int i = 0; i < (ROWS * N / 4) / 64; ++i) {   // 10 iters
        int idx = i * 64 + t;
        int rr  = idx / (N / 4);
        int q   = idx - rr * (N / 4);
        int col = q * 4;
        floatx4 v  = __builtin_nontemporal_load(
                         (const floatx4*)(tile + (size_t)rr * N + col));
        const float4 dv = *(const float4*)(h0d + col);
        sA[rr][col + 0] = v.x + dv.x;
        sA[rr][col + 1] = v.y + dv.y;
        sA[rr][col + 2] = v.z + dv.z;
        sA[rr][col + 3] = v.w + dv.w;
    }
    __syncthreads();   // single-wave block: cheap; nothing global pending

    const int  r   = t & 31;
    const bool isA = (t < 32);

    float str_[MID - 1], sti_[MID - 1];   // 39 stored CF terms (e_j / c_j)
    float2 X;
    X = make_float2(sA[r][isA ? 0 : (N - 1)], -1.0f);   // F_0 = d_0 / W_{N-1} = d_{N-1}

    // ---- phase 1: 39 steps, store e_{s+1} (A) / c_{78-s} (B) at [s] ----
    #pragma unroll
    for (int s = 0; s < MID - 1; ++s) {
        int col = isA ? (s + 1) : (N - 2 - s);          // d-index being consumed
        int bci = isA ? s : (N - 2 - s);                // bc-index
        float inv  = __builtin_amdgcn_rcpf(X.x * X.x + X.y * X.y);
        float binv = sBC[bci] * inv;
        float ex =  binv * X.x;
        float ey = -binv * X.y;
        str_[s] = ex; sti_[s] = ey;
        X.x = sA[r][col] - ex;                          // F_{s+1} / W_{78-s}
        X.y = -1.0f - ey;
    }

    // ---- handoff: A gets W_40, B gets F_39 (in-wave, no barrier) ----
    X.x = __shfl_xor(X.x, 32);
    X.y = __shfl_xor(X.y, 32);

    // ---- phase 2: finish opposite recursion, emit G, flush every 8 cols ----
    #pragma unroll
    for (int b8 = 0; b8 < 5; ++b8) {
        #pragma unroll
        for (int u = 0; u < 8; ++u) {
            const int u2  = b8 * 8 + u;
            const int j   = isA ? (MID - 1 - u2) : (MID + u2);   // 39..0 / 40..79
            const int bci = isA ? (MID - 1 - u2) : (MID - 1 + u2);
            float inv  = __builtin_amdgcn_rcpf(X.x * X.x + X.y * X.y);
            float binv = sBC[bci] * inv;
            float tx =  binv * X.x;                     // c_j (A) / e_j (B)
            float ty = -binv * X.y;
            float a  = sA[r][j];
            float Xx = a - tx;                          // W_j (A) / F_j (B)
            float Xy = -1.0f - ty;
            const int si = (u2 < MID - 1) ? (MID - 2 - u2) : 0;  // clamped (no str_[-1])
            float ox = (u2 < MID - 1) ? str_[si] : 0.0f;
            float oy = (u2 < MID - 1) ? sti_[si] : 0.0f;
            float zx = Xx - ox;                         // 1/G_j
            float zy = Xy - oy;
            float gi = __builtin_amdgcn_rcpf(zx * zx + zy * zy);
            const int slot = isA ? (j & 7) : (8 + (j & 7));
            sO[r][slot] = make_float2(zx * gi, -zy * gi);
            X.x = Xx; X.y = Xy;
        }
        // wave-synchronous flush: 2 full 64B lines per 8-lane group, no barrier
        #pragma unroll
        for (int i = 0; i < 4; ++i) {
            int idx = i * 64 + t;
            int rr  = idx >> 3;
            int u   = idx & 7;
            int col = (u < 4) ? (MID - 8 - 8 * b8 + 2 * u)    // A chunk: 32-8*b8 ..
                              : (MID - 8 + 8 * b8 + 2 * u);   // B chunk: 40+8*b8 ..
            float2 g0 = sO[rr][2 * u];
            float2 g1 = sO[rr][2 * u + 1];
            floatx4 w; w.x = g0.x; w.y = g0.y; w.z = g1.x; w.w = g1.y;
            __builtin_nontemporal_store(
                w, (floatx4*)(otile + (size_t)rr * N + col));
        }
    }
}

// ================= generic fallback (round-1 kernel, any N) ==================
__global__ __launch_bounds__(256) void greens_generic(
    const float* __restrict__ he,
    const float* __restrict__ h0d,
    const float* __restrict__ h0sub,
    const float* __restrict__ h0sup,
    float2* __restrict__ out,
    int Bn, int N)
{
    __shared__ float sa[MAXN];
    __shared__ float sbc[MAXN];
    const int t = threadIdx.x;
    if (t < N)     sa[t]  = h0d[t];
    if (t < N - 1) sbc[t] = h0sub[t] * h0sup[t];
    __syncthreads();

    const int b = blockIdx.x * blockDim.x + t;
    if (b >= Bn) return;

    const float* __restrict__ row  = he  + (size_t)b * N;
    float2*      __restrict__ orow = out + (size_t)b * N;

    double tpr = 1.0, tpi = 0.0;
    double tcr = (double)sa[0] + (double)row[0];
    double tci = -1.0;
    orow[0] = make_float2(1.0f, 0.0f);
    for (int k = 1; k < N; ++k) {
        orow[k] = make_float2((float)tcr, (float)tci);
        double ak = (double)sa[k] + (double)row[k];
        double bk = (double)sbc[k - 1];
        double nr = fma(ak, tcr,  tci) - bk * tpr;
        double ni = fma(ak, tci, -tcr) - bk * tpi;
        tpr = tcr; tpi = tci; tcr = nr; tci = ni;
    }
    const double dr = tcr, di = tci;
    const double inv = 1.0 / (dr * dr + di * di);
    const double cr  =  dr * inv;
    const double ci_ = -di * inv;

    double f1r = 1.0, f1i = 0.0;
    double f2r = 0.0, f2i = 0.0;
    for (int j = N - 1; j >= 0; --j) {
        float2 thv = orow[j];
        double tr = (double)thv.x, ti = (double)thv.y;
        double nr = tr * f1r - ti * f1i;
        double ni = tr * f1i + ti * f1r;
        orow[j] = make_float2((float)(nr * cr - ni * ci_),
                              (float)(nr * ci_ + ni * cr));
        double aj = (double)sa[j] + (double)row[j];
        double bj = (j < N - 1) ? (double)sbc[j] : 0.0;
        double pr = fma(aj, f1r,  f1i) - bj * f2r;
        double pi = fma(aj, f1i, -f1r) - bj * f2i;
        f2r = f1r; f2i = f1i; f1r = pr; f1i = pi;
    }
}

extern "C" void kernel_launch(void* const* d_in, const int* in_sizes, int n_in,
                              void* d_out, int out_size, void* d_ws, size_t ws_size,
                              hipStream_t stream) {
    const float* he    = (const float*)d_in[0];
    const float* h0d   = (const float*)d_in[1];
    const float* h0sub = (const float*)d_in[2];
    const float* h0sup = (const float*)d_in[3];
    const int N  = in_sizes[1];           // 80
    const int Bn = in_sizes[0] / N;       // 131072
    float2* out = (float2*)d_out;

    if (N == 80 && (Bn % 32) == 0) {
        const int grid = Bn / 32;
        hipLaunchKernelGGL((greens_cf1w<80>), dim3(grid), dim3(64), 0, stream,
                           he, h0d, h0sub, h0sup, out);
    } else {
        const int block = 256;
        const int grid  = (Bn + block - 1) / block;
        hipLaunchKernelGGL(greens_generic, dim3(grid), dim3(block), 0, stream,
                           he, h0d, h0sub, h0sup, out, Bn, N);
    }
}

// Round 4
// 126.921 us; speedup vs baseline: 1.3869x; 1.0379x over previous
//
#include <hip/hip_runtime.h>

#define MAXN 128

// native 16B vector type for nontemporal builtins (HIP float4 is a class)
typedef float floatx4 __attribute__((ext_vector_type(4)));

// ===== continued-fraction kernel: single-wave blocks, 2 lanes/row, fp32 ======
// 1/G_j = d_j - e_j - c_j,  e_j = bc_{j-1}/F_{j-1},  c_j = bc_j/W_{j+1}
// F_j = d_j - e_j (ratio theta_{j+1}/theta_j), W_j = d_j - c_j (phi_j/phi_{j+1})
// Im(F),Im(W) <= -1 always => O(1) magnitudes, fp32 + v_rcp stable.
// Lanes 0-31 (A) run forward on rows 0-31; lanes 32-63 (B) run backward on the
// same rows. Handoff F_39 <-> W_40 via shfl_xor(32). Branchless direction via
// lane-selected indices. No __syncthreads in the main loop (wave-synchronous).
//
// v5: occupancy lever, registers untouched (v2's spill lesson). Output is
// flushed every 4 columns instead of 8: sO [32][17] -> [32][9] float2, LDS
// 15.0KB -> 12.99KB => 12 blocks/CU (was 10). Stores go through L2 (no nt)
// so adjacent 32B half-line flushes merge into full 64B lines; nt stays on
// the touch-once he loads. Kernel is memory-stream-bound (floor ~19.7us,
// measured ~27us); +20% residency smooths the bursty per-CU request stream.
template<int N>
__global__ __launch_bounds__(64, 4) void greens_cf1w(
    const float* __restrict__ he,    // (B, N)
    const float* __restrict__ h0d,   // (N)
    const float* __restrict__ h0sub, // (N-1)
    const float* __restrict__ h0sup, // (N-1)
    float2* __restrict__ out)        // (B, N)
{
    constexpr int ROWS = 32;
    constexpr int MID  = N / 2;      // 40
    static_assert(N == 80, "tuned for N=80");

    __shared__ float  sA[ROWS][N + 1];   // a = h0d + he; pad 81 -> conflict-free
    __shared__ float2 sO[ROWS][9];       // staging: slots 0-3 A, 4-7 B, 8 pad
    __shared__ float  sBC[N];            // bc_j, j=0..N-2

    const int t = threadIdx.x;
    if (t < N - 1)      sBC[t]      = h0sub[t] * h0sup[t];
    if (t + 64 < N - 1) sBC[t + 64] = h0sub[t + 64] * h0sup[t + 64];

    const int row0 = blockIdx.x * ROWS;
    const float* __restrict__ tile  = he  + (size_t)row0 * N;
    float2*      __restrict__ otile = out + (size_t)row0 * N;

    // ---- stage a-tile, coalesced float4 (64 lanes x 16B = 1KB/instr) ----
    #pragma unroll
    for (int i = 0; i < (ROWS * N / 4) / 64; ++i) {   // 10 iters
        int idx = i * 64 + t;
        int rr  = idx / (N / 4);
        int q   = idx - rr * (N / 4);
        int col = q * 4;
        floatx4 v  = __builtin_nontemporal_load(
                         (const floatx4*)(tile + (size_t)rr * N + col));
        const float4 dv = *(const float4*)(h0d + col);
        sA[rr][col + 0] = v.x + dv.x;
        sA[rr][col + 1] = v.y + dv.y;
        sA[rr][col + 2] = v.z + dv.z;
        sA[rr][col + 3] = v.w + dv.w;
    }
    __syncthreads();   // single-wave block: cheap; nothing global pending

    const int  r   = t & 31;
    const bool isA = (t < 32);

    float str_[MID - 1], sti_[MID - 1];   // 39 stored CF terms (e_j / c_j)
    float2 X;
    X = make_float2(sA[r][isA ? 0 : (N - 1)], -1.0f);   // F_0 = d_0 / W_{N-1} = d_{N-1}

    // ---- phase 1: 39 steps, store e_{s+1} (A) / c_{78-s} (B) at [s] ----
    #pragma unroll
    for (int s = 0; s < MID - 1; ++s) {
        int col = isA ? (s + 1) : (N - 2 - s);          // d-index being consumed
        int bci = isA ? s : (N - 2 - s);                // bc-index
        float inv  = __builtin_amdgcn_rcpf(X.x * X.x + X.y * X.y);
        float binv = sBC[bci] * inv;
        float ex =  binv * X.x;
        float ey = -binv * X.y;
        str_[s] = ex; sti_[s] = ey;
        X.x = sA[r][col] - ex;                          // F_{s+1} / W_{78-s}
        X.y = -1.0f - ey;
    }

    // ---- handoff: A gets W_40, B gets F_39 (in-wave, no barrier) ----
    X.x = __shfl_xor(X.x, 32);
    X.y = __shfl_xor(X.y, 32);

    // ---- phase 2: finish opposite recursion, emit G, flush every 4 cols ----
    #pragma unroll
    for (int b4 = 0; b4 < 10; ++b4) {
        #pragma unroll
        for (int u = 0; u < 4; ++u) {
            const int u2  = b4 * 4 + u;
            const int j   = isA ? (MID - 1 - u2) : (MID + u2);   // 39..0 / 40..79
            const int bci = isA ? (MID - 1 - u2) : (MID - 1 + u2);
            float inv  = __builtin_amdgcn_rcpf(X.x * X.x + X.y * X.y);
            float binv = sBC[bci] * inv;
            float tx =  binv * X.x;                     // c_j (A) / e_j (B)
            float ty = -binv * X.y;
            float a  = sA[r][j];
            float Xx = a - tx;                          // W_j (A) / F_j (B)
            float Xy = -1.0f - ty;
            const int si = (u2 < MID - 1) ? (MID - 2 - u2) : 0;  // clamped (no str_[-1])
            float ox = (u2 < MID - 1) ? str_[si] : 0.0f;
            float oy = (u2 < MID - 1) ? sti_[si] : 0.0f;
            float zx = Xx - ox;                         // 1/G_j
            float zy = Xy - oy;
            float gi = __builtin_amdgcn_rcpf(zx * zx + zy * zy);
            const int slot = isA ? (j & 3) : (4 + (j & 3));
            sO[r][slot] = make_float2(zx * gi, -zy * gi);
            X.x = Xx; X.y = Xy;
        }
        // wave-synchronous flush: 32 rows x 64B (32B A-chunk + 32B B-chunk),
        // 2 iters x 64 lanes x 16B. L2 merges adjacent groups into full lines.
        #pragma unroll
        for (int i = 0; i < 2; ++i) {
            int idx = i * 64 + t;
            int rr  = idx >> 2;                         // 4 lanes per row
            int u   = idx & 3;
            int col = (u < 2) ? (MID - 4 - 4 * b4 + 2 * u)        // A: base 36-4*b4
                              : (MID + 4 * b4 + 2 * (u - 2));     // B: base 40+4*b4
            float2 g0 = sO[rr][2 * u];                  // slots 0-3 (A) / 4-7 (B)
            float2 g1 = sO[rr][2 * u + 1];
            *(float4*)(otile + (size_t)rr * N + col) =
                make_float4(g0.x, g0.y, g1.x, g1.y);
        }
    }
}

// ================= generic fallback (round-1 kernel, any N) ==================
__global__ __launch_bounds__(256) void greens_generic(
    const float* __restrict__ he,
    const float* __restrict__ h0d,
    const float* __restrict__ h0sub,
    const float* __restrict__ h0sup,
    float2* __restrict__ out,
    int Bn, int N)
{
    __shared__ float sa[MAXN];
    __shared__ float sbc[MAXN];
    const int t = threadIdx.x;
    if (t < N)     sa[t]  = h0d[t];
    if (t < N - 1) sbc[t] = h0sub[t] * h0sup[t];
    __syncthreads();

    const int b = blockIdx.x * blockDim.x + t;
    if (b >= Bn) return;

    const float* __restrict__ row  = he  + (size_t)b * N;
    float2*      __restrict__ orow = out + (size_t)b * N;

    double tpr = 1.0, tpi = 0.0;
    double tcr = (double)sa[0] + (double)row[0];
    double tci = -1.0;
    orow[0] = make_float2(1.0f, 0.0f);
    for (int k = 1; k < N; ++k) {
        orow[k] = make_float2((float)tcr, (float)tci);
        double ak = (double)sa[k] + (double)row[k];
        double bk = (double)sbc[k - 1];
        double nr = fma(ak, tcr,  tci) - bk * tpr;
        double ni = fma(ak, tci, -tcr) - bk * tpi;
        tpr = tcr; tpi = tci; tcr = nr; tci = ni;
    }
    const double dr = tcr, di = tci;
    const double inv = 1.0 / (dr * dr + di * di);
    const double cr  =  dr * inv;
    const double ci_ = -di * inv;

    double f1r = 1.0, f1i = 0.0;
    double f2r = 0.0, f2i = 0.0;
    for (int j = N - 1; j >= 0; --j) {
        float2 thv = orow[j];
        double tr = (double)thv.x, ti = (double)thv.y;
        double nr = tr * f1r - ti * f1i;
        double ni = tr * f1i + ti * f1r;
        orow[j] = make_float2((float)(nr * cr - ni * ci_),
                              (float)(nr * ci_ + ni * cr));
        double aj = (double)sa[j] + (double)row[j];
        double bj = (j < N - 1) ? (double)sbc[j] : 0.0;
        double pr = fma(aj, f1r,  f1i) - bj * f2r;
        double pi = fma(aj, f1i, -f1r) - bj * f2i;
        f2r = f1r; f2i = f1i; f1r = pr; f1i = pi;
    }
}

extern "C" void kernel_launch(void* const* d_in, const int* in_sizes, int n_in,
                              void* d_out, int out_size, void* d_ws, size_t ws_size,
                              hipStream_t stream) {
    const float* he    = (const float*)d_in[0];
    const float* h0d   = (const float*)d_in[1];
    const float* h0sub = (const float*)d_in[2];
    const float* h0sup = (const float*)d_in[3];
    const int N  = in_sizes[1];           // 80
    const int Bn = in_sizes[0] / N;       // 131072
    float2* out = (float2*)d_out;

    if (N == 80 && (Bn % 32) == 0) {
        const int grid = Bn / 32;
        hipLaunchKernelGGL((greens_cf1w<80>), dim3(grid), dim3(64), 0, stream,
                           he, h0d, h0sub, h0sup, out);
    } else {
        const int block = 256;
        const int grid  = (Bn + block - 1) / block;
        hipLaunchKernelGGL(greens_generic, dim3(grid), dim3(block), 0, stream,
                           he, h0d, h0sub, h0sup, out, Bn, N);
    }
}